// Round 17
// baseline (159.266 us; speedup 1.0000x reference)
//
#include <hip/hip_runtime.h>
#include <hip/hip_bf16.h>
#include <math.h>

// Problem constants
#define B 8
#define L 128
#define D 200
#define NROWS 2048          // 2 sequences * B * L
#define PAD_ID 1
#define LOG2E 1.4426950408889634f

__device__ __forceinline__ float fast_elu(float v) {
    return (v > 0.f) ? v : (__builtin_amdgcn_exp2f(v * LOG2E) - 1.0f);
}

// ==================== K1: fused emb->h->proj3 (4 rows/block, grid 512) =============
__global__ __launch_bounds__(256)
void fused_hproj_k(const int* __restrict__ x1, const int* __restrict__ x2,
                   const float* __restrict__ emb,
                   const float* __restrict__ Wh_w, const float* __restrict__ Wh_b,
                   const float* __restrict__ W1_w, const float* __restrict__ W2_w,
                   const float* __restrict__ Wf2_w, const float* __restrict__ bvec,
                   const float* __restrict__ Wf2_b, const float* __restrict__ cptr,
                   float* __restrict__ h, float* __restrict__ hP)
{
    __shared__ float As[4][200];
    __shared__ float Hs[4][200];
    const int r0 = blockIdx.x * 4;
    const int tid = threadIdx.x;

    for (int idx = tid; idx < 800; idx += 256) {
        const int r = idx / 200, k = idx - r * 200;
        const int row = r0 + r;
        const int id = (row < 1024) ? x1[row] : x2[row - 1024];
        As[r][k] = emb[id * 200 + k];
    }
    __syncthreads();

    const int c = tid;
    if (c < 200) {
        float acc[4] = {};
        for (int k4 = 0; k4 < 50; ++k4) {
            float a[4][4];
            #pragma unroll
            for (int r = 0; r < 4; ++r) {
                const float4 v = *(const float4*)&As[r][k4 * 4];
                a[r][0] = v.x; a[r][1] = v.y; a[r][2] = v.z; a[r][3] = v.w;
            }
            #pragma unroll
            for (int kk = 0; kk < 4; ++kk) {
                const float w = Wh_w[(k4 * 4 + kk) * 200 + c];
                #pragma unroll
                for (int r = 0; r < 4; ++r) acc[r] = fmaf(a[r][kk], w, acc[r]);
            }
        }
        const float bb = Wh_b[c];
        #pragma unroll
        for (int r = 0; r < 4; ++r) {
            float v = fast_elu(acc[r] + bb);
            Hs[r][c] = v;
            h[(r0 + r) * 200 + c] = v;
        }
    }
    __syncthreads();
    if (c < 200) {
        float a1[4] = {}, a2[4] = {}, a3[4] = {};
        for (int k4 = 0; k4 < 50; ++k4) {
            float a[4][4];
            #pragma unroll
            for (int r = 0; r < 4; ++r) {
                const float4 v = *(const float4*)&Hs[r][k4 * 4];
                a[r][0] = v.x; a[r][1] = v.y; a[r][2] = v.z; a[r][3] = v.w;
            }
            #pragma unroll
            for (int kk = 0; kk < 4; ++kk) {
                const int k = k4 * 4 + kk;
                const float w1 = W1_w[k * 200 + c];
                const float w2 = W2_w[k * 200 + c];
                const float w3 = Wf2_w[k * 200 + c];
                #pragma unroll
                for (int r = 0; r < 4; ++r) {
                    a1[r] = fmaf(a[r][kk], w1, a1[r]);
                    a2[r] = fmaf(a[r][kk], w2, a2[r]);
                    a3[r] = fmaf(a[r][kk], w3, a3[r]);
                }
            }
        }
        const float k1 = 2.0f * LOG2E / cptr[0];
        const float bv_ = bvec[c], wb = Wf2_b[c];
        #pragma unroll
        for (int r = 0; r < 4; ++r) {
            hP[(r0 + r) * 600 + c]       = (a1[r] + bv_) * k1;
            hP[(r0 + r) * 600 + 200 + c] = a2[r] * k1;
            hP[(r0 + r) * 600 + 400 + c] = a3[r] + wb;
        }
    }
}

// ==================== K2: attention partials (4 queries x 32 keys) ====================
__global__ __launch_bounds__(256)
void attn_part4_k(const float* __restrict__ h, const float* __restrict__ hP,
                  const float* __restrict__ cptr,
                  const int* __restrict__ x1, const int* __restrict__ x2,
                  float* __restrict__ part, float* __restrict__ hsumP)
{
    const int blk = blockIdx.x;          // 0..2047
    const int jq  = blk & 3;
    const int qc  = (blk >> 2) & 31;
    const int sb  = blk >> 7;            // 0..15
    const int i0  = qc * 4;
    const int base = sb * 128;
    const int j0 = jq * 32, j1 = j0 + 32;
    const int d = threadIdx.x;
    const int* ids = (sb < 8) ? x1 : x2;
    const int loc0 = (sb & 7) * 128;

    const float cval = cptr[0];
    const float mcoef = -2.0f * cval * LOG2E;

    const unsigned long long km =
        __ballot(ids[loc0 + j0 + (threadIdx.x & 31)] == PAD_ID);

    float pq[4];
    #pragma unroll
    for (int q = 0; q < 4; ++q)
        pq[q] = (d < D) ? hP[(base + i0 + q) * 600 + d] : 0.f;

    float lf[4] = {}, af[4] = {}, lb[4] = {}, ab[4] = {};
    float hsum = 0.f;

    auto sc = [&](float p, float h2k) -> float {
        float e2 = __builtin_amdgcn_exp2f(p + h2k);
        return __builtin_amdgcn_exp2f(mcoef * __builtin_amdgcn_rcpf(e2 + 1.0f));
    };
    auto ldrow = [&](int j, float& h2k, float& hj) {
        h2k = 0.f; hj = 0.f;
        if (d < D) {
            h2k = hP[(base + j) * 600 + 200 + d];
            hj  = h[(base + j) * 200 + d];
        }
    };

    const int aEnd = (i0 < j1) ? i0 : j1;
    for (int j = j0; j < aEnd; j += 2) {
        float h2a, ha, h2b, hb;
        ldrow(j, h2a, ha); ldrow(j + 1, h2b, hb);
        hsum += ha + hb;
        if (!((km >> (j - j0)) & 1ull)) {
            #pragma unroll
            for (int q = 0; q < 4; ++q) {
                float w = sc(pq[q], h2a);
                lb[q] += w; ab[q] = fmaf(w, ha, ab[q]);
            }
        }
        if (!((km >> (j + 1 - j0)) & 1ull)) {
            #pragma unroll
            for (int q = 0; q < 4; ++q) {
                float w = sc(pq[q], h2b);
                lb[q] += w; ab[q] = fmaf(w, hb, ab[q]);
            }
        }
    }
    if (i0 >= j0 && i0 < j1) {
        #pragma unroll
        for (int jj = 0; jj < 4; ++jj) {
            const int j = i0 + jj;
            float h2a, ha;
            ldrow(j, h2a, ha);
            hsum += ha;
            if (!((km >> (j - j0)) & 1ull)) {
                #pragma unroll
                for (int q = 0; q < 4; ++q) {
                    if (jj == q) continue;
                    float w = sc(pq[q], h2a);
                    if (jj > q) { lf[q] += w; af[q] = fmaf(w, ha, af[q]); }
                    else        { lb[q] += w; ab[q] = fmaf(w, ha, ab[q]); }
                }
            }
        }
    }
    const int cs = (i0 + 4 > j0) ? i0 + 4 : j0;
    for (int j = cs; j < j1; j += 2) {
        float h2a, ha, h2b, hb;
        ldrow(j, h2a, ha); ldrow(j + 1, h2b, hb);
        hsum += ha + hb;
        if (!((km >> (j - j0)) & 1ull)) {
            #pragma unroll
            for (int q = 0; q < 4; ++q) {
                float w = sc(pq[q], h2a);
                lf[q] += w; af[q] = fmaf(w, ha, af[q]);
            }
        }
        if (!((km >> (j + 1 - j0)) & 1ull)) {
            #pragma unroll
            for (int q = 0; q < 4; ++q) {
                float w = sc(pq[q], h2b);
                lf[q] += w; af[q] = fmaf(w, hb, af[q]);
            }
        }
    }

    if (d < D) {
        float* pp = part + (size_t)blk * 3200;   // [blk][16][200]
        #pragma unroll
        for (int q = 0; q < 4; ++q) {
            pp[(q * 4 + 0) * 200 + d] = lf[q];
            pp[(q * 4 + 1) * 200 + d] = af[q];
            pp[(q * 4 + 2) * 200 + d] = lb[q];
            pp[(q * 4 + 3) * 200 + d] = ab[q];
        }
        hsumP[(jq * 16 + sb) * 200 + d] = hsum;
    }
}

// ==================== K3: fused post-attention (r11 config: 4 rows, 256 thr) ========
__global__ __launch_bounds__(256)
void fused_post_k(const float* __restrict__ P, const float* __restrict__ hsumP,
                  const int* __restrict__ x1, const int* __restrict__ x2,
                  const float* __restrict__ h, const float* __restrict__ hP,
                  const float* __restrict__ Wf1_w,
                  const float* __restrict__ Ws1_w, const float* __restrict__ Ws1_b,
                  const float* __restrict__ Ws_w, const float* __restrict__ Ws_b,
                  float* __restrict__ bvP)
{
    __shared__ float sS[8][200];    // 4 fw rows | 4 bw rows
    __shared__ float uS[4][400];
    __shared__ float v1S[4][400];
    const int bid = blockIdx.x;       // 0..511
    const int sb = bid >> 5;          // 0..15
    const int qp = bid & 31;          // 0..31
    const int i0 = qp * 4;
    const int base = sb * 128;
    const int tid = threadIdx.x;
    const int* ids = (sb < 8) ? x1 : x2;
    const int loc0 = (sb & 7) * 128;
    const int c = tid;

    // Phase 1: combine attention partials -> s rows
    if (c < 200) {
        float hs = 0.f;
        #pragma unroll
        for (int jq = 0; jq < 4; ++jq) hs += hsumP[(jq * 16 + sb) * 200 + c];
        const float fb = hs * (1.0f / 128.0f);
        #pragma unroll
        for (int q = 0; q < 4; ++q) {
            const bool mi = (ids[loc0 + i0 + q] == PAD_ID);
            float lf = 0.f, af = 0.f, lb = 0.f, ab = 0.f;
            #pragma unroll
            for (int jq = 0; jq < 4; ++jq) {
                const float* pp = P + (size_t)(sb * 128 + qp * 4 + jq) * 3200
                                    + (q * 4) * 200;
                lf += pp[c]; af += pp[200 + c]; lb += pp[400 + c]; ab += pp[600 + c];
            }
            sS[q][c]     = (!mi && lf > 0.f) ? af / lf : fb;
            sS[4 + q][c] = (!mi && lb > 0.f) ? ab / lb : fb;
        }
    }
    __syncthreads();

    // Phase 2: g = s @ Wf1 (8 rows x 200 cols, K=200); gate -> uS
    if (c < 200) {
        float acc[8] = {};
        for (int k4 = 0; k4 < 50; ++k4) {
            float a[8][4];
            #pragma unroll
            for (int r = 0; r < 8; ++r) {
                const float4 v = *(const float4*)&sS[r][k4 * 4];
                a[r][0] = v.x; a[r][1] = v.y; a[r][2] = v.z; a[r][3] = v.w;
            }
            #pragma unroll
            for (int kk = 0; kk < 4; ++kk) {
                const float w = Wf1_w[(k4 * 4 + kk) * 200 + c];
                #pragma unroll
                for (int r = 0; r < 8; ++r) acc[r] = fmaf(a[r][kk], w, acc[r]);
            }
        }
        #pragma unroll
        for (int q = 0; q < 4; ++q) {
            const int sr = base + i0 + q;
            const float hf2 = hP[sr * 600 + 400 + c];
            const float hv  = h[sr * 200 + c];
            const float ffw = 1.0f / (1.0f + __expf(-(acc[q] + hf2)));
            const float fbw = 1.0f / (1.0f + __expf(-(acc[4 + q] + hf2)));
            uS[q][c]       = ffw * hv + (1.f - ffw) * sS[q][c];
            uS[q][200 + c] = fbw * hv + (1.f - fbw) * sS[4 + q][c];
        }
    }
    __syncthreads();

    // Phase 3: v1 = elu(u @ Ws1 + b)  (4 rows x 400 cols, K=400); cols c, c+200
    if (c < 200) {
        float a0[4] = {}, a1[4] = {};
        for (int k4 = 0; k4 < 100; ++k4) {
            float a[4][4];
            #pragma unroll
            for (int r = 0; r < 4; ++r) {
                const float4 v = *(const float4*)&uS[r][k4 * 4];
                a[r][0] = v.x; a[r][1] = v.y; a[r][2] = v.z; a[r][3] = v.w;
            }
            #pragma unroll
            for (int kk = 0; kk < 4; ++kk) {
                const int k = k4 * 4 + kk;
                const float w0 = Ws1_w[k * 400 + c];
                const float w1 = Ws1_w[k * 400 + c + 200];
                #pragma unroll
                for (int r = 0; r < 4; ++r) {
                    a0[r] = fmaf(a[r][kk], w0, a0[r]);
                    a1[r] = fmaf(a[r][kk], w1, a1[r]);
                }
            }
        }
        const float b0 = Ws1_b[c], b1 = Ws1_b[c + 200];
        #pragma unroll
        for (int r = 0; r < 4; ++r) {
            v1S[r][c]       = fast_elu(a0[r] + b0);
            v1S[r][c + 200] = fast_elu(a1[r] + b1);
        }
    }
    __syncthreads();

    // Phase 4: atts = v1 @ Ws + b; bv partial = sum_r u*atts
    if (c < 200) {
        float a0[4] = {}, a1[4] = {};
        for (int k4 = 0; k4 < 100; ++k4) {
            float a[4][4];
            #pragma unroll
            for (int r = 0; r < 4; ++r) {
                const float4 v = *(const float4*)&v1S[r][k4 * 4];
                a[r][0] = v.x; a[r][1] = v.y; a[r][2] = v.z; a[r][3] = v.w;
            }
            #pragma unroll
            for (int kk = 0; kk < 4; ++kk) {
                const int k = k4 * 4 + kk;
                const float w0 = Ws_w[k * 400 + c];
                const float w1 = Ws_w[k * 400 + c + 200];
                #pragma unroll
                for (int r = 0; r < 4; ++r) {
                    a0[r] = fmaf(a[r][kk], w0, a0[r]);
                    a1[r] = fmaf(a[r][kk], w1, a1[r]);
                }
            }
        }
        const float b0 = Ws_b[c], b1 = Ws_b[c + 200];
        float s0 = 0.f, s1 = 0.f;
        #pragma unroll
        for (int r = 0; r < 4; ++r) {
            s0 = fmaf(uS[r][c],       a0[r] + b0, s0);
            s1 = fmaf(uS[r][c + 200], a1[r] + b1, s1);
        }
        bvP[bid * 400 + c]       = s0;
        bvP[bid * 400 + c + 200] = s1;
    }
}

// ==================== K4: merged final MLP ====================
// bvP: [512][400], index (sb*32 + qp). One block per batch b (8 blocks).
__global__ __launch_bounds__(256)
void final_k(const float* __restrict__ bvP, const float* __restrict__ F1w,
             const float* __restrict__ F1b, const float* __restrict__ F2w,
             const float* __restrict__ F2b, float* __restrict__ y)
{
    __shared__ float cvS[400];
    __shared__ float rvS[400];
    __shared__ float red[256];
    const int b = blockIdx.x;       // 0..7
    const int tid = threadIdx.x;

    for (int kk = tid; kk < 400; kk += 256) {
        float cv = 0.f, rv = 0.f;
        #pragma unroll 8
        for (int p = 0; p < 32; ++p) {
            cv += bvP[(b * 32 + p) * 400 + kk];
            rv += bvP[((8 + b) * 32 + p) * 400 + kk];
        }
        cvS[kk] = cv;
        rvS[kk] = rv;
    }
    __syncthreads();

    float v = 0.f;
    if (tid < 200) {
        float acc = F1b[tid];
        for (int k = 0; k < 400; ++k) {
            const float cv = cvS[k], rv = rvS[k];
            acc = fmaf(cv,      F1w[k * 200 + tid],          acc);
            acc = fmaf(rv,      F1w[(400 + k) * 200 + tid],  acc);
            acc = fmaf(cv - rv, F1w[(800 + k) * 200 + tid],  acc);
            acc = fmaf(cv * rv, F1w[(1200 + k) * 200 + tid], acc);
        }
        v = fmaxf(acc, 0.f) * F2w[tid];
    }
    red[tid] = v;
    __syncthreads();
    for (int off = 128; off; off >>= 1) {
        if (tid < off) red[tid] += red[tid + off];
        __syncthreads();
    }
    if (tid == 0) y[b] = red[0] + F2b[0];
}

extern "C" void kernel_launch(void* const* d_in, const int* in_sizes, int n_in,
                              void* d_out, int out_size, void* d_ws, size_t ws_size,
                              hipStream_t stream)
{
    const int*   x1    = (const int*)d_in[0];
    const int*   x2    = (const int*)d_in[1];
    const float* emb   = (const float*)d_in[2];
    const float* Wh_w  = (const float*)d_in[3];
    const float* Wh_b  = (const float*)d_in[4];
    const float* W1_w  = (const float*)d_in[5];
    const float* W2_w  = (const float*)d_in[6];
    const float* bvec  = (const float*)d_in[7];
    const float* cptr  = (const float*)d_in[8];
    const float* Wf1_w = (const float*)d_in[9];
    const float* Wf2_w = (const float*)d_in[10];
    const float* Wf2_b = (const float*)d_in[11];
    const float* Ws1_w = (const float*)d_in[12];
    const float* Ws1_b = (const float*)d_in[13];
    const float* Ws_w  = (const float*)d_in[14];
    const float* Ws_b  = (const float*)d_in[15];
    const float* F1_w  = (const float*)d_in[16];
    const float* F1_b  = (const float*)d_in[17];
    const float* F2_w  = (const float*)d_in[18];
    const float* F2_b  = (const float*)d_in[19];
    float* y = (float*)d_out;

    float* ws = (float*)d_ws;
    float* h     = ws;                    // 409600
    float* hP    = h     + 409600;        // 1228800
    float* hsumP = hP    + 1228800;       // 12800
    float* bvP   = hsumP + 12800;         // 204800 (512*400)
    float* P     = bvP   + 204800;        // 6553600 (attention partials)

    fused_hproj_k<<<dim3(512), dim3(256), 0, stream>>>(
        x1, x2, emb, Wh_w, Wh_b, W1_w, W2_w, Wf2_w, bvec, Wf2_b, cptr, h, hP);
    attn_part4_k<<<dim3(2048), dim3(256), 0, stream>>>(h, hP, cptr, x1, x2, P, hsumP);
    fused_post_k<<<dim3(512), dim3(256), 0, stream>>>(
        P, hsumP, x1, x2, h, hP, Wf1_w, Ws1_w, Ws1_b, Ws_w, Ws_b, bvP);
    final_k<<<dim3(8), dim3(256), 0, stream>>>(bvP, F1_w, F1_b, F2_w, F2_b, y);
}

// Round 18
// 142.210 us; speedup vs baseline: 1.1199x; 1.1199x over previous
//
#include <hip/hip_runtime.h>
#include <hip/hip_bf16.h>
#include <math.h>

// Problem constants
#define B 8
#define L 128
#define D 200
#define NROWS 2048          // 2 sequences * B * L
#define PAD_ID 1
#define LOG2E 1.4426950408889634f

__device__ __forceinline__ float fast_elu(float v) {
    return (v > 0.f) ? v : (__builtin_amdgcn_exp2f(v * LOG2E) - 1.0f);
}

// ==================== K1: fused emb->h->proj3 (2 rows/block, grid 1024) =============
__global__ __launch_bounds__(256)
void fused_hproj_k(const int* __restrict__ x1, const int* __restrict__ x2,
                   const float* __restrict__ emb,
                   const float* __restrict__ Wh_w, const float* __restrict__ Wh_b,
                   const float* __restrict__ W1_w, const float* __restrict__ W2_w,
                   const float* __restrict__ Wf2_w, const float* __restrict__ bvec,
                   const float* __restrict__ Wf2_b, const float* __restrict__ cptr,
                   float* __restrict__ h, float* __restrict__ hP)
{
    __shared__ float As[2][200];
    __shared__ float Hs[2][200];
    const int r0 = blockIdx.x * 2;
    const int tid = threadIdx.x;

    for (int idx = tid; idx < 400; idx += 256) {
        const int r = idx / 200, k = idx - r * 200;
        const int row = r0 + r;
        const int id = (row < 1024) ? x1[row] : x2[row - 1024];
        As[r][k] = emb[id * 200 + k];
    }
    __syncthreads();

    const int c = tid;
    if (c < 200) {
        float acc[2] = {};
        for (int k4 = 0; k4 < 50; ++k4) {
            float a[2][4];
            #pragma unroll
            for (int r = 0; r < 2; ++r) {
                const float4 v = *(const float4*)&As[r][k4 * 4];
                a[r][0] = v.x; a[r][1] = v.y; a[r][2] = v.z; a[r][3] = v.w;
            }
            #pragma unroll
            for (int kk = 0; kk < 4; ++kk) {
                const float w = Wh_w[(k4 * 4 + kk) * 200 + c];
                #pragma unroll
                for (int r = 0; r < 2; ++r) acc[r] = fmaf(a[r][kk], w, acc[r]);
            }
        }
        const float bb = Wh_b[c];
        #pragma unroll
        for (int r = 0; r < 2; ++r) {
            float v = fast_elu(acc[r] + bb);
            Hs[r][c] = v;
            h[(r0 + r) * 200 + c] = v;
        }
    }
    __syncthreads();
    if (c < 200) {
        float a1[2] = {}, a2[2] = {}, a3[2] = {};
        for (int k4 = 0; k4 < 50; ++k4) {
            float a[2][4];
            #pragma unroll
            for (int r = 0; r < 2; ++r) {
                const float4 v = *(const float4*)&Hs[r][k4 * 4];
                a[r][0] = v.x; a[r][1] = v.y; a[r][2] = v.z; a[r][3] = v.w;
            }
            #pragma unroll
            for (int kk = 0; kk < 4; ++kk) {
                const int k = k4 * 4 + kk;
                const float w1 = W1_w[k * 200 + c];
                const float w2 = W2_w[k * 200 + c];
                const float w3 = Wf2_w[k * 200 + c];
                #pragma unroll
                for (int r = 0; r < 2; ++r) {
                    a1[r] = fmaf(a[r][kk], w1, a1[r]);
                    a2[r] = fmaf(a[r][kk], w2, a2[r]);
                    a3[r] = fmaf(a[r][kk], w3, a3[r]);
                }
            }
        }
        const float k1 = 2.0f * LOG2E / cptr[0];
        const float bv_ = bvec[c], wb = Wf2_b[c];
        #pragma unroll
        for (int r = 0; r < 2; ++r) {
            hP[(r0 + r) * 600 + c]       = (a1[r] + bv_) * k1;
            hP[(r0 + r) * 600 + 200 + c] = a2[r] * k1;
            hP[(r0 + r) * 600 + 400 + c] = a3[r] + wb;
        }
    }
}

// ==================== K2: attention partials (4 queries x 32 keys) ====================
__global__ __launch_bounds__(256)
void attn_part4_k(const float* __restrict__ h, const float* __restrict__ hP,
                  const float* __restrict__ cptr,
                  const int* __restrict__ x1, const int* __restrict__ x2,
                  float* __restrict__ part, float* __restrict__ hsumP)
{
    const int blk = blockIdx.x;          // 0..2047
    const int jq  = blk & 3;
    const int qc  = (blk >> 2) & 31;
    const int sb  = blk >> 7;            // 0..15
    const int i0  = qc * 4;
    const int base = sb * 128;
    const int j0 = jq * 32, j1 = j0 + 32;
    const int d = threadIdx.x;
    const int* ids = (sb < 8) ? x1 : x2;
    const int loc0 = (sb & 7) * 128;

    const float cval = cptr[0];
    const float mcoef = -2.0f * cval * LOG2E;

    const unsigned long long km =
        __ballot(ids[loc0 + j0 + (threadIdx.x & 31)] == PAD_ID);

    float pq[4];
    #pragma unroll
    for (int q = 0; q < 4; ++q)
        pq[q] = (d < D) ? hP[(base + i0 + q) * 600 + d] : 0.f;

    float lf[4] = {}, af[4] = {}, lb[4] = {}, ab[4] = {};
    float hsum = 0.f;

    auto sc = [&](float p, float h2k) -> float {
        float e2 = __builtin_amdgcn_exp2f(p + h2k);
        return __builtin_amdgcn_exp2f(mcoef * __builtin_amdgcn_rcpf(e2 + 1.0f));
    };
    auto ldrow = [&](int j, float& h2k, float& hj) {
        h2k = 0.f; hj = 0.f;
        if (d < D) {
            h2k = hP[(base + j) * 600 + 200 + d];
            hj  = h[(base + j) * 200 + d];
        }
    };

    const int aEnd = (i0 < j1) ? i0 : j1;
    for (int j = j0; j < aEnd; j += 2) {
        float h2a, ha, h2b, hb;
        ldrow(j, h2a, ha); ldrow(j + 1, h2b, hb);
        hsum += ha + hb;
        if (!((km >> (j - j0)) & 1ull)) {
            #pragma unroll
            for (int q = 0; q < 4; ++q) {
                float w = sc(pq[q], h2a);
                lb[q] += w; ab[q] = fmaf(w, ha, ab[q]);
            }
        }
        if (!((km >> (j + 1 - j0)) & 1ull)) {
            #pragma unroll
            for (int q = 0; q < 4; ++q) {
                float w = sc(pq[q], h2b);
                lb[q] += w; ab[q] = fmaf(w, hb, ab[q]);
            }
        }
    }
    if (i0 >= j0 && i0 < j1) {
        #pragma unroll
        for (int jj = 0; jj < 4; ++jj) {
            const int j = i0 + jj;
            float h2a, ha;
            ldrow(j, h2a, ha);
            hsum += ha;
            if (!((km >> (j - j0)) & 1ull)) {
                #pragma unroll
                for (int q = 0; q < 4; ++q) {
                    if (jj == q) continue;
                    float w = sc(pq[q], h2a);
                    if (jj > q) { lf[q] += w; af[q] = fmaf(w, ha, af[q]); }
                    else        { lb[q] += w; ab[q] = fmaf(w, ha, ab[q]); }
                }
            }
        }
    }
    const int cs = (i0 + 4 > j0) ? i0 + 4 : j0;
    for (int j = cs; j < j1; j += 2) {
        float h2a, ha, h2b, hb;
        ldrow(j, h2a, ha); ldrow(j + 1, h2b, hb);
        hsum += ha + hb;
        if (!((km >> (j - j0)) & 1ull)) {
            #pragma unroll
            for (int q = 0; q < 4; ++q) {
                float w = sc(pq[q], h2a);
                lf[q] += w; af[q] = fmaf(w, ha, af[q]);
            }
        }
        if (!((km >> (j + 1 - j0)) & 1ull)) {
            #pragma unroll
            for (int q = 0; q < 4; ++q) {
                float w = sc(pq[q], h2b);
                lf[q] += w; af[q] = fmaf(w, hb, af[q]);
            }
        }
    }

    if (d < D) {
        float* pp = part + (size_t)blk * 3200;   // [blk][16][200]
        #pragma unroll
        for (int q = 0; q < 4; ++q) {
            pp[(q * 4 + 0) * 200 + d] = lf[q];
            pp[(q * 4 + 1) * 200 + d] = af[q];
            pp[(q * 4 + 2) * 200 + d] = lb[q];
            pp[(q * 4 + 3) * 200 + d] = ab[q];
        }
        hsumP[(jq * 16 + sb) * 200 + d] = hsum;
    }
}

// ==================== K3: fused post-attention (4 rows/block, grid 512, 256 thr) =====
__global__ __launch_bounds__(256)
void fused_post_k(const float* __restrict__ P, const float* __restrict__ hsumP,
                  const int* __restrict__ x1, const int* __restrict__ x2,
                  const float* __restrict__ h, const float* __restrict__ hP,
                  const float* __restrict__ Wf1_w,
                  const float* __restrict__ Ws1_w, const float* __restrict__ Ws1_b,
                  const float* __restrict__ Ws_w, const float* __restrict__ Ws_b,
                  float* __restrict__ bvP)
{
    __shared__ float sS[8][200];    // 4 fw rows | 4 bw rows
    __shared__ float uS[4][400];
    __shared__ float v1S[4][400];
    const int bid = blockIdx.x;       // 0..511
    const int sb = bid >> 5;          // 0..15
    const int qp = bid & 31;          // 0..31
    const int i0 = qp * 4;
    const int base = sb * 128;
    const int tid = threadIdx.x;
    const int* ids = (sb < 8) ? x1 : x2;
    const int loc0 = (sb & 7) * 128;
    const int c = tid;

    // Phase 1: combine attention partials -> s rows
    if (c < 200) {
        float hs = 0.f;
        #pragma unroll
        for (int jq = 0; jq < 4; ++jq) hs += hsumP[(jq * 16 + sb) * 200 + c];
        const float fb = hs * (1.0f / 128.0f);
        #pragma unroll
        for (int q = 0; q < 4; ++q) {
            const bool mi = (ids[loc0 + i0 + q] == PAD_ID);
            float lf = 0.f, af = 0.f, lb = 0.f, ab = 0.f;
            #pragma unroll
            for (int jq = 0; jq < 4; ++jq) {
                const float* pp = P + (size_t)(sb * 128 + qp * 4 + jq) * 3200
                                    + (q * 4) * 200;
                lf += pp[c]; af += pp[200 + c]; lb += pp[400 + c]; ab += pp[600 + c];
            }
            sS[q][c]     = (!mi && lf > 0.f) ? af / lf : fb;
            sS[4 + q][c] = (!mi && lb > 0.f) ? ab / lb : fb;
        }
    }
    __syncthreads();

    // Phase 2: g = s @ Wf1 (8 rows x 200 cols, K=200); gate -> uS
    if (c < 200) {
        float acc[8] = {};
        for (int k4 = 0; k4 < 50; ++k4) {
            float a[8][4];
            #pragma unroll
            for (int r = 0; r < 8; ++r) {
                const float4 v = *(const float4*)&sS[r][k4 * 4];
                a[r][0] = v.x; a[r][1] = v.y; a[r][2] = v.z; a[r][3] = v.w;
            }
            #pragma unroll
            for (int kk = 0; kk < 4; ++kk) {
                const float w = Wf1_w[(k4 * 4 + kk) * 200 + c];
                #pragma unroll
                for (int r = 0; r < 8; ++r) acc[r] = fmaf(a[r][kk], w, acc[r]);
            }
        }
        #pragma unroll
        for (int q = 0; q < 4; ++q) {
            const int sr = base + i0 + q;
            const float hf2 = hP[sr * 600 + 400 + c];
            const float hv  = h[sr * 200 + c];
            const float ffw = 1.0f / (1.0f + __expf(-(acc[q] + hf2)));
            const float fbw = 1.0f / (1.0f + __expf(-(acc[4 + q] + hf2)));
            uS[q][c]       = ffw * hv + (1.f - ffw) * sS[q][c];
            uS[q][200 + c] = fbw * hv + (1.f - fbw) * sS[4 + q][c];
        }
    }
    __syncthreads();

    // Phase 3: v1 = elu(u @ Ws1 + b)  (4 rows x 400 cols, K=400); cols c, c+200
    if (c < 200) {
        float a0[4] = {}, a1[4] = {};
        for (int k4 = 0; k4 < 100; ++k4) {
            float a[4][4];
            #pragma unroll
            for (int r = 0; r < 4; ++r) {
                const float4 v = *(const float4*)&uS[r][k4 * 4];
                a[r][0] = v.x; a[r][1] = v.y; a[r][2] = v.z; a[r][3] = v.w;
            }
            #pragma unroll
            for (int kk = 0; kk < 4; ++kk) {
                const int k = k4 * 4 + kk;
                const float w0 = Ws1_w[k * 400 + c];
                const float w1 = Ws1_w[k * 400 + c + 200];
                #pragma unroll
                for (int r = 0; r < 4; ++r) {
                    a0[r] = fmaf(a[r][kk], w0, a0[r]);
                    a1[r] = fmaf(a[r][kk], w1, a1[r]);
                }
            }
        }
        const float b0 = Ws1_b[c], b1 = Ws1_b[c + 200];
        #pragma unroll
        for (int r = 0; r < 4; ++r) {
            v1S[r][c]       = fast_elu(a0[r] + b0);
            v1S[r][c + 200] = fast_elu(a1[r] + b1);
        }
    }
    __syncthreads();

    // Phase 4: atts = v1 @ Ws + b; bv partial = sum_r u*atts
    if (c < 200) {
        float a0[4] = {}, a1[4] = {};
        for (int k4 = 0; k4 < 100; ++k4) {
            float a[4][4];
            #pragma unroll
            for (int r = 0; r < 4; ++r) {
                const float4 v = *(const float4*)&v1S[r][k4 * 4];
                a[r][0] = v.x; a[r][1] = v.y; a[r][2] = v.z; a[r][3] = v.w;
            }
            #pragma unroll
            for (int kk = 0; kk < 4; ++kk) {
                const int k = k4 * 4 + kk;
                const float w0 = Ws_w[k * 400 + c];
                const float w1 = Ws_w[k * 400 + c + 200];
                #pragma unroll
                for (int r = 0; r < 4; ++r) {
                    a0[r] = fmaf(a[r][kk], w0, a0[r]);
                    a1[r] = fmaf(a[r][kk], w1, a1[r]);
                }
            }
        }
        const float b0 = Ws_b[c], b1 = Ws_b[c + 200];
        float s0 = 0.f, s1 = 0.f;
        #pragma unroll
        for (int r = 0; r < 4; ++r) {
            const float2 uv0 = make_float2(uS[r][c], uS[r][c + 200]);
            s0 = fmaf(uv0.x, a0[r] + b0, s0);
            s1 = fmaf(uv0.y, a1[r] + b1, s1);
        }
        bvP[bid * 400 + c]       = s0;
        bvP[bid * 400 + c + 200] = s1;
    }
}

// ==================== K4/K5: final MLP (r11 split version) ====================
// bvP: [512][400], block (sb*32 + qp). bv[sb] = sum over 32 qp parts.
__global__ __launch_bounds__(256)
void final1_part_k(const float* __restrict__ bvP, const float* __restrict__ F1w,
                   float* __restrict__ part)
{
    __shared__ float feats[8][50];
    const int bid = blockIdx.x;       // 0..31
    const int seg = bid >> 3;
    const int kr0 = (bid & 7) * 50;
    const int tid = threadIdx.x;
    for (int idx = tid; idx < 400; idx += 256) {
        const int b = idx / 50, kk = idx - b * 50;
        float cv = 0.f, rv = 0.f;
        #pragma unroll 8
        for (int p = 0; p < 32; ++p) {
            cv += bvP[(b * 32 + p) * 400 + kr0 + kk];
            rv += bvP[((8 + b) * 32 + p) * 400 + kr0 + kk];
        }
        feats[b][kk] = (seg == 0) ? cv : (seg == 1) ? rv
                     : (seg == 2) ? (cv - rv) : (cv * rv);
    }
    __syncthreads();
    const int n = tid;
    if (n >= 200) return;
    const int kbase = seg * 400 + kr0;
    float acc[8] = {};
    #pragma unroll 5
    for (int kk = 0; kk < 50; ++kk) {
        const float w = F1w[(kbase + kk) * 200 + n];
        #pragma unroll
        for (int b = 0; b < 8; ++b)
            acc[b] = fmaf(feats[b][kk], w, acc[b]);
    }
    #pragma unroll
    for (int b = 0; b < 8; ++b)
        part[(bid * 8 + b) * 200 + n] = acc[b];
}

__global__ __launch_bounds__(256)
void final2_k(const float* __restrict__ part, const float* __restrict__ F1b,
              const float* __restrict__ F2w, const float* __restrict__ F2b,
              float* __restrict__ y)
{
    __shared__ float red[256];
    const int b = blockIdx.x, tid = threadIdx.x;
    float v = 0.f;
    if (tid < 200) {
        float s = F1b[tid];
        #pragma unroll 8
        for (int t = 0; t < 32; ++t)
            s += part[(t * 8 + b) * 200 + tid];
        v = fmaxf(s, 0.f) * F2w[tid];
    }
    red[tid] = v;
    __syncthreads();
    for (int off = 128; off; off >>= 1) {
        if (tid < off) red[tid] += red[tid + off];
        __syncthreads();
    }
    if (tid == 0) y[b] = red[0] + F2b[0];
}

extern "C" void kernel_launch(void* const* d_in, const int* in_sizes, int n_in,
                              void* d_out, int out_size, void* d_ws, size_t ws_size,
                              hipStream_t stream)
{
    const int*   x1    = (const int*)d_in[0];
    const int*   x2    = (const int*)d_in[1];
    const float* emb   = (const float*)d_in[2];
    const float* Wh_w  = (const float*)d_in[3];
    const float* Wh_b  = (const float*)d_in[4];
    const float* W1_w  = (const float*)d_in[5];
    const float* W2_w  = (const float*)d_in[6];
    const float* bvec  = (const float*)d_in[7];
    const float* cptr  = (const float*)d_in[8];
    const float* Wf1_w = (const float*)d_in[9];
    const float* Wf2_w = (const float*)d_in[10];
    const float* Wf2_b = (const float*)d_in[11];
    const float* Ws1_w = (const float*)d_in[12];
    const float* Ws1_b = (const float*)d_in[13];
    const float* Ws_w  = (const float*)d_in[14];
    const float* Ws_b  = (const float*)d_in[15];
    const float* F1_w  = (const float*)d_in[16];
    const float* F1_b  = (const float*)d_in[17];
    const float* F2_w  = (const float*)d_in[18];
    const float* F2_b  = (const float*)d_in[19];
    float* y = (float*)d_out;

    float* ws = (float*)d_ws;
    float* h     = ws;                    // 409600
    float* hP    = h     + 409600;        // 1228800
    float* hsumP = hP    + 1228800;       // 12800
    float* bvP   = hsumP + 12800;         // 204800 (512*400)
    float* partM = bvP   + 204800;        // 51200
    float* P     = partM + 51200;         // 6553600 (attention partials)

    fused_hproj_k<<<dim3(1024), dim3(256), 0, stream>>>(
        x1, x2, emb, Wh_w, Wh_b, W1_w, W2_w, Wf2_w, bvec, Wf2_b, cptr, h, hP);
    attn_part4_k<<<dim3(2048), dim3(256), 0, stream>>>(h, hP, cptr, x1, x2, P, hsumP);
    fused_post_k<<<dim3(512), dim3(256), 0, stream>>>(
        P, hsumP, x1, x2, h, hP, Wf1_w, Ws1_w, Ws1_b, Ws_w, Ws_b, bvP);
    final1_part_k<<<dim3(32), dim3(256), 0, stream>>>(bvP, F1_w, partM);
    final2_k<<<dim3(8), dim3(256), 0, stream>>>(partM, F1_b, F2_w, F2_b, y);
}